// Round 2
// baseline (633.752 us; speedup 1.0000x reference)
//
#include <hip/hip_runtime.h>

// AUGRU fused scan, MI355X/gfx950.  I/O is FP32 (reference is jnp.float32;
// R1's NaN came from misreading fp32 buffers as bf16).
//
//  - One wave (64 lanes) per batch row; lane j owns h_j (fp32 across steps).
//  - Per-lane weight columns cached in VGPRs as packed f16 pairs along k
//    (fp32 -> f16 quantization: rel err ~5e-4, far under the 1.94e-2 thresh).
//  - v_dot2_f32_f16 (2 MAC/lane/instr) for all matmul work.
//  - LDS used only for wave-internal broadcast of x / h / r*h. Single wave
//    per block + in-order DS pipe => no s_barrier needed; wave_barrier() is
//    a compiler-only ordering fence. b16 writes = 2-way bank alias (free),
//    half2 reads are same-address broadcast (free).
//  - Early exit at seq_len (masked region: out=0, h frozen => dead work),
//    then vectorized 16B zero-fill of the tail.
//  - x(t) prefetched 2 steps ahead (clamped index stays in-bounds).

typedef _Float16 half2_t __attribute__((ext_vector_type(2)));

#define T_MAX 200
#define H_DIM 64

__device__ __forceinline__ half2_t mkf(float a, float b) {
    half2_t h;
    h[0] = (_Float16)a;
    h[1] = (_Float16)b;
    return h;
}
__device__ __forceinline__ float dot2f(half2_t a, half2_t b, float c) {
#if __has_builtin(__builtin_amdgcn_fdot2)
    return __builtin_amdgcn_fdot2(a, b, c, false);   // v_dot2_f32_f16
#else
    return fmaf((float)a[1], (float)b[1], fmaf((float)a[0], (float)b[0], c));
#endif
}

__global__ __launch_bounds__(64, 2) void augru_fused(
    const float* __restrict__ X,    // (B,200,64) fp32
    const int*   __restrict__ SL,   // (B,1) int32
    const float* __restrict__ ATT,  // (B,200,1) fp32
    const float* __restrict__ WG,   // (128,128) fp32
    const float* __restrict__ BG,   // (128,) fp32
    const float* __restrict__ WC,   // (128,64) fp32
    const float* __restrict__ BC,   // (64,) fp32
    float*       __restrict__ OUT)  // (B,200,64) fp32
{
    const int b = blockIdx.x;
    const int j = threadIdx.x;       // 0..63 : h-component / output column

    int L = SL[b];
    if (L > T_MAX) L = T_MAX;
    if (L < 0) L = 0;

    __shared__ half2_t sxv[32];   // x(t)  as f16 pairs along k
    __shared__ half2_t shv[32];   // h(t)  as f16 pairs
    __shared__ half2_t srhv[32];  // r*h   as f16 pairs
    _Float16* sxh = (_Float16*)sxv;
    _Float16* sh  = (_Float16*)shv;
    _Float16* srh = (_Float16*)srhv;

    const size_t rowoff = (size_t)b * T_MAX * H_DIM;
    float* outrow = OUT + rowoff;

    if (L > 0) {
        // ---- weight columns -> registers (192 packed-f16 dwords) ----
        half2_t wgr0[32], wgr1[32], wgu0[32], wgu1[32], wcx[32], wch[32];
#pragma unroll
        for (int p = 0; p < 32; ++p) {
            const int k0 = 2 * p, k1 = 2 * p + 1;
            wgr0[p] = mkf(WG[k0 * 128 + j],             WG[k1 * 128 + j]);
            wgu0[p] = mkf(WG[k0 * 128 + 64 + j],        WG[k1 * 128 + 64 + j]);
            wgr1[p] = mkf(WG[(64 + k0) * 128 + j],      WG[(64 + k1) * 128 + j]);
            wgu1[p] = mkf(WG[(64 + k0) * 128 + 64 + j], WG[(64 + k1) * 128 + 64 + j]);
            wcx[p]  = mkf(WC[k0 * 64 + j],              WC[k1 * 64 + j]);
            wch[p]  = mkf(WC[(64 + k0) * 64 + j],       WC[(64 + k1) * 64 + j]);
        }
        const float bgr = BG[j];
        const float bgu = BG[64 + j];
        const float bcj = BC[j];

        const float* xrow = X + rowoff;
        const float* arow = ATT + (size_t)b * T_MAX;

        // ---- 2-deep prefetch pipeline (lane j loads x element j) ----
        const int t1 = (L > 1) ? 1 : 0;
        float xcur = xrow[j];            // x(0)_j
        float xnxt = xrow[t1 * 64 + j];  // x(1)_j
        float a0   = arow[0];
        float a1   = arow[t1];

        sxh[j] = (_Float16)xcur;         // stage x(0)
        __builtin_amdgcn_wave_barrier();

        float h = 0.0f;
        for (int t = 0; t < L; ++t) {
            int tp = t + 2; if (tp > T_MAX - 1) tp = T_MAX - 1;  // clamped, in-bounds
            float xpre = xrow[tp * 64 + j];                      // prefetch x(t+2)
            float apre = arow[tp];                               // prefetch a(t+2)

            sh[j] = (_Float16)h;
            __builtin_amdgcn_wave_barrier();

            // gate + cand-x accumulation
            float accr = bgr, accu = bgu, accc = bcj;
#pragma unroll
            for (int p = 0; p < 32; ++p) {           // k = 0..63 : x part
                half2_t xp = sxv[p];
                accr = dot2f(xp, wgr0[p], accr);
                accu = dot2f(xp, wgu0[p], accu);
                accc = dot2f(xp, wcx[p],  accc);
            }
#pragma unroll
            for (int p = 0; p < 32; ++p) {           // k = 64..127 : h part
                half2_t hp = shv[p];
                accr = dot2f(hp, wgr1[p], accr);
                accu = dot2f(hp, wgu1[p], accu);
            }

            float r = __fdividef(1.0f, 1.0f + __expf(-accr));
            float u = __fdividef(1.0f, 1.0f + __expf(-accu));

            srh[j] = (_Float16)(r * h);
            __builtin_amdgcn_wave_barrier();
#pragma unroll
            for (int p = 0; p < 32; ++p) {           // cand: r*h part
                accc = dot2f(srhv[p], wch[p], accc);
            }

            // c = tanh(accc), overflow-safe
            float ax = fabsf(accc);
            float e2 = __expf(2.0f * ax);
            float c  = copysignf(1.0f - __fdividef(2.0f, e2 + 1.0f), accc);

            float uu = (1.0f - a0) * u;
            h = c + uu * (h - c);                    // u*h + (1-u)*c

            outrow[t * H_DIM + j] = h;

            sxh[j] = (_Float16)xnxt;                 // stage x(t+1)
            __builtin_amdgcn_wave_barrier();
            xcur = xnxt;
            xnxt = xpre;
            a0   = a1;
            a1   = apre;
        }
    }

    // ---- zero-fill masked tail t in [L, 200) with 16B stores ----
    {
        uint4 z = make_uint4(0u, 0u, 0u, 0u);
        uint4* zp = (uint4*)(outrow + L * H_DIM);    // L*256 bytes: 16B-aligned
        const int n4 = (T_MAX - L) * (H_DIM / 4);    // 16B chunks
        for (int i = j; i < n4; i += 64) zp[i] = z;
    }
}

extern "C" void kernel_launch(void* const* d_in, const int* in_sizes, int n_in,
                              void* d_out, int out_size, void* d_ws, size_t ws_size,
                              hipStream_t stream) {
    const float* X   = (const float*)d_in[0];
    const int*   SL  = (const int*)d_in[1];
    const float* ATT = (const float*)d_in[2];
    const float* WG  = (const float*)d_in[3];
    const float* BG  = (const float*)d_in[4];
    const float* WC  = (const float*)d_in[5];
    const float* BC  = (const float*)d_in[6];
    float*       OUT = (float*)d_out;

    const int B = in_sizes[1];   // sequence_length has B*1 elements
    dim3 grid(B), block(64);
    augru_fused<<<grid, block, 0, stream>>>(X, SL, ATT, WG, BG, WC, BC, OUT);
}

// Round 4
// 630.655 us; speedup vs baseline: 1.0049x; 1.0049x over previous
//
#include <hip/hip_runtime.h>

// AUGRU fused scan, MI355X/gfx950.  R4 (= R3 with compile fix).
//
// R2 post-mortem: VGPR_Count=128 proved the 192 packed-f16 weight dwords were
// NOT in arch VGPRs (AGPR demotion => +192 v_accvgpr_read/step, matches
// VALUBusy 44% and 415us). Also 96 ds_read_b32 broadcast reads/step saturate
// the per-CU DS pipe (~557 cyc/wave-step).
//
// Changes vs R2:
//  - Weights pinned into arch VGPRs via empty asm "+v" constraints.
//  - LDS broadcasts read as half8 (ds_read_b128): 96 -> 24 DS ops/step.
//    half2 extraction via ext-vector .lo/.hi swizzles (parse-time constant;
//    __builtin_shufflevector with loop-var indices does not compile).

typedef _Float16 half2_t __attribute__((ext_vector_type(2)));
typedef _Float16 half8_t __attribute__((ext_vector_type(8)));

#define T_MAX 200
#define H_DIM 64

__device__ __forceinline__ half2_t mkf(float a, float b) {
    half2_t h;
    h[0] = (_Float16)a;
    h[1] = (_Float16)b;
    return h;
}
__device__ __forceinline__ float dot2f(half2_t a, half2_t b, float c) {
#if __has_builtin(__builtin_amdgcn_fdot2)
    return __builtin_amdgcn_fdot2(a, b, c, false);   // v_dot2_f32_f16
#else
    return fmaf((float)a[1], (float)b[1], fmaf((float)a[0], (float)b[0], c));
#endif
}

__global__ __launch_bounds__(64, 2) void augru_fused(
    const float* __restrict__ X,    // (B,200,64) fp32
    const int*   __restrict__ SL,   // (B,1) int32
    const float* __restrict__ ATT,  // (B,200,1) fp32
    const float* __restrict__ WG,   // (128,128) fp32
    const float* __restrict__ BG,   // (128,) fp32
    const float* __restrict__ WC,   // (128,64) fp32
    const float* __restrict__ BC,   // (64,) fp32
    float*       __restrict__ OUT)  // (B,200,64) fp32
{
    const int b = blockIdx.x;
    const int j = threadIdx.x;       // 0..63 : h-component / output column

    int L = SL[b];
    if (L > T_MAX) L = T_MAX;
    if (L < 0) L = 0;

    __shared__ half8_t sx8[8];    // x(t)  as f16, 128B
    __shared__ half8_t sh8[8];    // h(t)  as f16
    __shared__ half8_t srh8[8];   // r*h   as f16
    _Float16* sxh = (_Float16*)sx8;
    _Float16* sh  = (_Float16*)sh8;
    _Float16* srh = (_Float16*)srh8;

    const size_t rowoff = (size_t)b * T_MAX * H_DIM;
    float* outrow = OUT + rowoff;

    if (L > 0) {
        // ---- weight columns -> arch VGPRs (192 packed-f16 dwords) ----
        half2_t wgr0[32], wgr1[32], wgu0[32], wgu1[32], wcx[32], wch[32];
#pragma unroll
        for (int p = 0; p < 32; ++p) {
            const int k0 = 2 * p, k1 = 2 * p + 1;
            wgr0[p] = mkf(WG[k0 * 128 + j],             WG[k1 * 128 + j]);
            wgu0[p] = mkf(WG[k0 * 128 + 64 + j],        WG[k1 * 128 + 64 + j]);
            wgr1[p] = mkf(WG[(64 + k0) * 128 + j],      WG[(64 + k1) * 128 + j]);
            wgu1[p] = mkf(WG[(64 + k0) * 128 + 64 + j], WG[(64 + k1) * 128 + 64 + j]);
            wcx[p]  = mkf(WC[k0 * 64 + j],              WC[k1 * 64 + j]);
            wch[p]  = mkf(WC[(64 + k0) * 64 + j],       WC[(64 + k1) * 64 + j]);
        }
        // Pin every weight dword into an arch VGPR: defeats AGPR demotion and
        // rematerialization (R2: VGPR_Count=128 proved they weren't resident).
#pragma unroll
        for (int p = 0; p < 32; ++p) {
            asm volatile("" : "+v"(wgr0[p]), "+v"(wgu0[p]), "+v"(wgr1[p]),
                              "+v"(wgu1[p]), "+v"(wcx[p]),  "+v"(wch[p]));
        }
        const float bgr = BG[j];
        const float bgu = BG[64 + j];
        const float bcj = BC[j];

        const float* xrow = X + rowoff;
        const float* arow = ATT + (size_t)b * T_MAX;

        // ---- 2-deep prefetch pipeline (lane j loads x element j) ----
        const int t1 = (L > 1) ? 1 : 0;
        float xcur = xrow[j];            // x(0)_j
        float xnxt = xrow[t1 * 64 + j];  // x(1)_j
        float a0   = arow[0];
        float a1   = arow[t1];

        sxh[j] = (_Float16)xcur;         // stage x(0)
        __builtin_amdgcn_wave_barrier();

        float h = 0.0f;
        for (int t = 0; t < L; ++t) {
            int tp = t + 2; if (tp > T_MAX - 1) tp = T_MAX - 1;  // clamped, in-bounds
            float xpre = xrow[tp * 64 + j];                      // prefetch x(t+2)
            float apre = arow[tp];                               // prefetch a(t+2)

            sh[j] = (_Float16)h;
            __builtin_amdgcn_wave_barrier();

            // gate + cand-x accumulation; broadcast operands via ds_read_b128
            float accr = bgr, accu = bgu, accc = bcj;
#pragma unroll
            for (int q = 0; q < 8; ++q) {            // k = 0..63 : x part
                half8_t xv = sx8[q];
                half2_t x0 = xv.lo.lo, x1 = xv.lo.hi, x2 = xv.hi.lo, x3 = xv.hi.hi;
                const int p = 4 * q;
                accr = dot2f(x0, wgr0[p + 0], accr);
                accu = dot2f(x0, wgu0[p + 0], accu);
                accc = dot2f(x0, wcx[p + 0],  accc);
                accr = dot2f(x1, wgr0[p + 1], accr);
                accu = dot2f(x1, wgu0[p + 1], accu);
                accc = dot2f(x1, wcx[p + 1],  accc);
                accr = dot2f(x2, wgr0[p + 2], accr);
                accu = dot2f(x2, wgu0[p + 2], accu);
                accc = dot2f(x2, wcx[p + 2],  accc);
                accr = dot2f(x3, wgr0[p + 3], accr);
                accu = dot2f(x3, wgu0[p + 3], accu);
                accc = dot2f(x3, wcx[p + 3],  accc);
            }
#pragma unroll
            for (int q = 0; q < 8; ++q) {            // k = 64..127 : h part
                half8_t hv = sh8[q];
                half2_t h0 = hv.lo.lo, h1 = hv.lo.hi, h2 = hv.hi.lo, h3 = hv.hi.hi;
                const int p = 4 * q;
                accr = dot2f(h0, wgr1[p + 0], accr);
                accu = dot2f(h0, wgu1[p + 0], accu);
                accr = dot2f(h1, wgr1[p + 1], accr);
                accu = dot2f(h1, wgu1[p + 1], accu);
                accr = dot2f(h2, wgr1[p + 2], accr);
                accu = dot2f(h2, wgu1[p + 2], accu);
                accr = dot2f(h3, wgr1[p + 3], accr);
                accu = dot2f(h3, wgu1[p + 3], accu);
            }

            float r = __fdividef(1.0f, 1.0f + __expf(-accr));
            float u = __fdividef(1.0f, 1.0f + __expf(-accu));

            srh[j] = (_Float16)(r * h);
            __builtin_amdgcn_wave_barrier();
#pragma unroll
            for (int q = 0; q < 8; ++q) {            // cand: r*h part
                half8_t rv = srh8[q];
                half2_t r0 = rv.lo.lo, r1 = rv.lo.hi, r2 = rv.hi.lo, r3 = rv.hi.hi;
                const int p = 4 * q;
                accc = dot2f(r0, wch[p + 0], accc);
                accc = dot2f(r1, wch[p + 1], accc);
                accc = dot2f(r2, wch[p + 2], accc);
                accc = dot2f(r3, wch[p + 3], accc);
            }

            // c = tanh(accc), overflow-safe
            float ax = fabsf(accc);
            float e2 = __expf(2.0f * ax);
            float c  = copysignf(1.0f - __fdividef(2.0f, e2 + 1.0f), accc);

            float uu = (1.0f - a0) * u;
            h = c + uu * (h - c);                    // u*h + (1-u)*c

            outrow[t * H_DIM + j] = h;

            sxh[j] = (_Float16)xnxt;                 // stage x(t+1)
            __builtin_amdgcn_wave_barrier();
            xcur = xnxt;
            xnxt = xpre;
            a0   = a1;
            a1   = apre;
        }
    }

    // ---- zero-fill masked tail t in [L, 200) with 16B stores ----
    {
        uint4 z = make_uint4(0u, 0u, 0u, 0u);
        uint4* zp = (uint4*)(outrow + L * H_DIM);    // L*256 bytes: 16B-aligned
        const int n4 = (T_MAX - L) * (H_DIM / 4);    // 16B chunks
        for (int i = j; i < n4; i += 64) zp[i] = z;
    }
}

extern "C" void kernel_launch(void* const* d_in, const int* in_sizes, int n_in,
                              void* d_out, int out_size, void* d_ws, size_t ws_size,
                              hipStream_t stream) {
    const float* X   = (const float*)d_in[0];
    const int*   SL  = (const int*)d_in[1];
    const float* ATT = (const float*)d_in[2];
    const float* WG  = (const float*)d_in[3];
    const float* BG  = (const float*)d_in[4];
    const float* WC  = (const float*)d_in[5];
    const float* BC  = (const float*)d_in[6];
    float*       OUT = (float*)d_out;

    const int B = in_sizes[1];   // sequence_length has B*1 elements
    dim3 grid(B), block(64);
    augru_fused<<<grid, block, 0, stream>>>(X, SL, ATT, WG, BG, WC, BC, OUT);
}